// Round 6
// baseline (119.801 us; speedup 1.0000x reference)
//
#include <hip/hip_runtime.h>

// Paillier sum-pooling = windowed modular product of ciphertexts mod n^2.
// M = NSQ = 46337^2 = 2147117569 < 2^31; inputs int32, output int32 (exact).
//
// Memory-bound: 537 MB read + 134 MB write. Round-5 structure (4 outputs/
// thread, per-instruction contiguous int4 loads) + grid-stride loop unrolled
// x2 with the pair separated by one full grid stride: doubles loads in
// flight per thread WITHOUT changing the per-instruction lane->address
// mapping (R4 showed adjacent-lane striding kills coalescing).
//
// Cheap exact mod: 2^31 = M + 366079 -> p mod M folds as
//   p -> (p>>31)*366079 + (p & 0x7FFFFFFF)
// bound chain 2^62.04 -> 2^49.6 -> 2^37.1 -> <= 2170912703 < 2M, closed under
// chaining; single conditional subtract at the end.

#define M   2147117569u
#define K31 366079ull          // 2^31 mod M

typedef int int4v __attribute__((ext_vector_type(4)));

__device__ __forceinline__ unsigned modmul31(unsigned a, unsigned b) {
    unsigned long long p = (unsigned long long)a * b;                                  // < 2^62.04
    p = (unsigned long long)(unsigned)(p >> 31) * K31 + (unsigned)(p & 0x7FFFFFFF);    // < 2^49.6
    p = (unsigned long long)(unsigned)(p >> 31) * K31 + (unsigned)(p & 0x7FFFFFFF);    // < 2^37.1
    p = (unsigned long long)(unsigned)(p >> 31) * K31 + (unsigned)(p & 0x7FFFFFFF);    // <= 2170912703
    return (unsigned)p;
}

__device__ __forceinline__ int in_base(int wi) {
    int flat = wi << 2;
    int c  = flat & 63;
    int wo = (flat >> 6) & 127;
    int ho = (flat >> 13) & 127;
    int b  = flat >> 20;
    // ((b*256 + 2*ho)*256 + 2*wo)*64 + c   (< 2^27, fits int)
    return ((((b << 8) + (ho << 1)) << 8) + (wo << 1)) * 64 + c;
}

__global__ __launch_bounds__(256) void paillier_pool_kernel(
    const int* __restrict__ x, int* __restrict__ out, int nwork)
{
    const int stride = gridDim.x * blockDim.x;               // 524288
    for (int wi = blockIdx.x * blockDim.x + threadIdx.x; wi < nwork; wi += 2 * stride) {
        const int wi2 = wi + stride;                         // nwork = 16*stride, always valid
        const int baseA = in_base(wi);
        const int baseB = in_base(wi2);

        // Issue all 8 loads before any dependent ALU: 8 in-flight VMEM ops.
        int4v a00 = __builtin_nontemporal_load((const int4v*)(x + baseA));
        int4v a01 = __builtin_nontemporal_load((const int4v*)(x + baseA + 64));
        int4v a10 = __builtin_nontemporal_load((const int4v*)(x + baseA + 16384));
        int4v a11 = __builtin_nontemporal_load((const int4v*)(x + baseA + 16448));
        int4v b00 = __builtin_nontemporal_load((const int4v*)(x + baseB));
        int4v b01 = __builtin_nontemporal_load((const int4v*)(x + baseB + 64));
        int4v b10 = __builtin_nontemporal_load((const int4v*)(x + baseB + 16384));
        int4v b11 = __builtin_nontemporal_load((const int4v*)(x + baseB + 16448));

        int4v ra, rb;
#pragma unroll
        for (int k = 0; k < 4; ++k) {
            unsigned t0 = modmul31((unsigned)a00[k], (unsigned)a01[k]);
            unsigned t1 = modmul31((unsigned)a10[k], (unsigned)a11[k]);
            unsigned t  = modmul31(t0, t1);
            if (t >= M) t -= M;
            ra[k] = (int)t;

            unsigned u0 = modmul31((unsigned)b00[k], (unsigned)b01[k]);
            unsigned u1 = modmul31((unsigned)b10[k], (unsigned)b11[k]);
            unsigned u  = modmul31(u0, u1);
            if (u >= M) u -= M;
            rb[k] = (int)u;
        }

        __builtin_nontemporal_store(ra, (int4v*)(out + (wi  << 2)));
        __builtin_nontemporal_store(rb, (int4v*)(out + (wi2 << 2)));
    }
}

extern "C" void kernel_launch(void* const* d_in, const int* in_sizes, int n_in,
                              void* d_out, int out_size, void* d_ws, size_t ws_size,
                              hipStream_t stream) {
    const int* x = (const int*)d_in[0];
    int* out = (int*)d_out;

    const int nwork = out_size / 4;      // 33554432 / 4 = 8388608
    const int block = 256;
    const int grid  = 2048;              // 8 blocks/CU; grid-stride, unroll x2 -> 8 iters

    paillier_pool_kernel<<<grid, block, 0, stream>>>(x, out, nwork);
}